// Round 2
// baseline (26.785 us; speedup 1.0000x reference)
//
#include <hip/hip_runtime.h>

#define NAG  6144
#define BLK  256
#define NJC  16                 // j-chunks
#define JCH  (NAG / NJC)        // 384 j's per chunk
#define DT   0.01f
#define SOFT 0.25f

// ---- kernel 1: partial LJ forces, one (i-block, j-chunk) per block ----
__global__ __launch_bounds__(BLK) void lj_partial(const float2* __restrict__ pos,
                                                  const float* __restrict__ eps_p,
                                                  const float* __restrict__ sig_p,
                                                  float2* __restrict__ partial) {
    __shared__ float2 sp[JCH];
    const int i  = blockIdx.x * BLK + threadIdx.x;
    const int jc = blockIdx.y;
    for (int t = threadIdx.x; t < JCH; t += BLK)
        sp[t] = pos[jc * JCH + t];
    __syncthreads();

    const float s  = *sig_p;
    const float s2 = s * s;
    const float k  = 24.0f * (*eps_p);
    const float2 pi = pos[i];

    float fx = 0.0f, fy = 0.0f;
#pragma unroll 8
    for (int j = 0; j < JCH; ++j) {
        const float dx  = pi.x - sp[j].x;
        const float dy  = pi.y - sp[j].y;
        const float r2s = fmaf(dx, dx, fmaf(dy, dy, SOFT));   // r^2 + SOFT
        const float inv = __builtin_amdgcn_rcpf(r2s);         // ~1 ulp rcp
        const float ir2 = s2 * inv;                           // (sigma/r)^2
        const float i6  = ir2 * ir2 * ir2;                    // (sigma/r)^6
        const float t   = fmaf(2.0f * i6, i6, -i6);           // 2*i12 - i6
        const float c   = k * t * inv;                        // 24*eps*(...)/r2s
        // j == i: dx = dy = 0 -> contributes exactly 0 (r2s = SOFT, finite)
        fx = fmaf(c, dx, fx);
        fy = fmaf(c, dy, fy);
    }
    partial[jc * NAG + i] = make_float2(fx, fy);
}

// ---- kernel 2: reduce partials + semi-implicit Euler + pack output ----
__global__ __launch_bounds__(BLK) void lj_integrate(const float2* __restrict__ pos,
                                                    const float2* __restrict__ vel,
                                                    const float2* __restrict__ partial,
                                                    float4* __restrict__ out) {
    const int i = blockIdx.x * BLK + threadIdx.x;
    float fx = 0.0f, fy = 0.0f;
#pragma unroll
    for (int c = 0; c < NJC; ++c) {
        const float2 p = partial[c * NAG + i];
        fx += p.x;
        fy += p.y;
    }
    const float2 v = vel[i];
    const float2 p = pos[i];
    const float vnx = fmaf(DT, fx, v.x);
    const float vny = fmaf(DT, fy, v.y);
    const float pnx = fmaf(DT, vnx, p.x);
    const float pny = fmaf(DT, vny, p.y);
    out[i] = make_float4(pnx, pny, vnx, vny);
}

// ---- fallback: single-pass (used only if ws_size is too small) ----
__global__ __launch_bounds__(BLK) void lj_onepass(const float2* __restrict__ pos,
                                                  const float2* __restrict__ vel,
                                                  const float* __restrict__ eps_p,
                                                  const float* __restrict__ sig_p,
                                                  float4* __restrict__ out) {
    __shared__ float2 sp[BLK];
    const int i = blockIdx.x * BLK + threadIdx.x;
    const float s  = *sig_p;
    const float s2 = s * s;
    const float k  = 24.0f * (*eps_p);
    const float2 pi = pos[i];
    float fx = 0.0f, fy = 0.0f;
    for (int tile = 0; tile < NAG; tile += BLK) {
        __syncthreads();
        sp[threadIdx.x] = pos[tile + threadIdx.x];
        __syncthreads();
#pragma unroll 8
        for (int j = 0; j < BLK; ++j) {
            const float dx  = pi.x - sp[j].x;
            const float dy  = pi.y - sp[j].y;
            const float r2s = fmaf(dx, dx, fmaf(dy, dy, SOFT));
            const float inv = __builtin_amdgcn_rcpf(r2s);
            const float ir2 = s2 * inv;
            const float i6  = ir2 * ir2 * ir2;
            const float t   = fmaf(2.0f * i6, i6, -i6);
            const float c   = k * t * inv;
            fx = fmaf(c, dx, fx);
            fy = fmaf(c, dy, fy);
        }
    }
    const float2 v = vel[i];
    const float vnx = fmaf(DT, fx, v.x);
    const float vny = fmaf(DT, fy, v.y);
    const float pnx = fmaf(DT, vnx, pi.x);
    const float pny = fmaf(DT, vny, pi.y);
    out[i] = make_float4(pnx, pny, vnx, vny);
}

extern "C" void kernel_launch(void* const* d_in, const int* in_sizes, int n_in,
                              void* d_out, int out_size, void* d_ws, size_t ws_size,
                              hipStream_t stream) {
    const float2* pos   = (const float2*)d_in[0];
    const float2* vel   = (const float2*)d_in[1];
    const float*  eps_p = (const float*)d_in[2];
    const float*  sig_p = (const float*)d_in[3];
    float4* out = (float4*)d_out;

    const size_t need = (size_t)NJC * NAG * sizeof(float2);
    if (ws_size >= need) {
        float2* partial = (float2*)d_ws;
        dim3 grid(NAG / BLK, NJC);
        lj_partial<<<grid, BLK, 0, stream>>>(pos, eps_p, sig_p, partial);
        lj_integrate<<<NAG / BLK, BLK, 0, stream>>>(pos, vel, partial, out);
    } else {
        lj_onepass<<<NAG / BLK, BLK, 0, stream>>>(pos, vel, eps_p, sig_p, out);
    }
}

// Round 3
// 23.599 us; speedup vs baseline: 1.1350x; 1.1350x over previous
//
#include <hip/hip_runtime.h>

#define NAG   6144
#define DT    0.01f
#define SOFT  0.25f

#define BLK1  256
#define IPT   2                  // i's per thread in kernel 1
#define IBLK  (BLK1 * IPT)       // 512 i's per block
#define NIB   (NAG / IBLK)       // 12 i-blocks
#define NJC   64                 // j-chunks
#define JCH   (NAG / NJC)        // 96 j's per chunk

// ---- kernel 1: partial LJ forces; block = (i-block, j-chunk); 2 i's/thread ----
__global__ __launch_bounds__(BLK1, 3) void lj_partial(
    const float4* __restrict__ pos4,
    const float2* __restrict__ pos2,
    const float*  __restrict__ eps_p,
    const float*  __restrict__ sig_p,
    float4* __restrict__ partial4)
{
    __shared__ float2 sp[JCH];
    const int tid = threadIdx.x;
    const int jc  = blockIdx.y;
    if (tid < JCH) sp[tid] = pos2[jc * JCH + tid];
    __syncthreads();

    const float eps  = *eps_p, s = *sig_p;
    const float s2   = s * s, s6 = s2 * s2 * s2;
    const float ke   = 24.0f * eps;
    const float ks12 = 2.0f * ke * s6 * s6;   // 48*eps*sigma^12
    const float mks6 = -ke * s6;              // -24*eps*sigma^6

    const int t4 = blockIdx.x * BLK1 + tid;   // float4 slot: i = 2*t4, 2*t4+1
    const float4 p = pos4[t4];

    float fx0 = 0.f, fy0 = 0.f, fx1 = 0.f, fy1 = 0.f;
#pragma unroll 8
    for (int j = 0; j < JCH; ++j) {
        const float2 pj = sp[j];
        {   // pair (i0, j):  coeff = u^4 * (ks12*u^3 - ks6),  u = 1/(r^2+SOFT)
            const float dx = p.x - pj.x, dy = p.y - pj.y;
            const float r  = fmaf(dx, dx, fmaf(dy, dy, SOFT));
            const float u  = __builtin_amdgcn_rcpf(r);
            const float u2 = u * u, u3 = u2 * u, u4 = u2 * u2;
            const float c  = u4 * fmaf(ks12, u3, mks6);
            fx0 = fmaf(c, dx, fx0); fy0 = fmaf(c, dy, fy0);  // j==i -> dx=dy=0 -> 0
        }
        {   // pair (i1, j)
            const float dx = p.z - pj.x, dy = p.w - pj.y;
            const float r  = fmaf(dx, dx, fmaf(dy, dy, SOFT));
            const float u  = __builtin_amdgcn_rcpf(r);
            const float u2 = u * u, u3 = u2 * u, u4 = u2 * u2;
            const float c  = u4 * fmaf(ks12, u3, mks6);
            fx1 = fmaf(c, dx, fx1); fy1 = fmaf(c, dy, fy1);
        }
    }
    partial4[jc * (NAG / 2) + t4] = make_float4(fx0, fy0, fx1, fy1);
}

// ---- kernel 2: reduce NJC partials + semi-implicit Euler + pack [pos,vel] ----
#define BLK2 128
__global__ __launch_bounds__(BLK2) void lj_integrate(
    const float4* __restrict__ pos4,
    const float4* __restrict__ vel4,
    const float4* __restrict__ partial4,
    float4* __restrict__ out4)
{
    const int t = blockIdx.x * BLK2 + threadIdx.x;    // t in [0, NAG/2)
    float fx0 = 0.f, fy0 = 0.f, fx1 = 0.f, fy1 = 0.f;
#pragma unroll 8
    for (int c = 0; c < NJC; ++c) {
        const float4 q = partial4[c * (NAG / 2) + t];
        fx0 += q.x; fy0 += q.y; fx1 += q.z; fy1 += q.w;
    }
    const float4 pv = pos4[t];
    const float4 vv = vel4[t];
    const float vnx0 = fmaf(DT, fx0, vv.x), vny0 = fmaf(DT, fy0, vv.y);
    const float vnx1 = fmaf(DT, fx1, vv.z), vny1 = fmaf(DT, fy1, vv.w);
    const float pnx0 = fmaf(DT, vnx0, pv.x), pny0 = fmaf(DT, vny0, pv.y);
    const float pnx1 = fmaf(DT, vnx1, pv.z), pny1 = fmaf(DT, vny1, pv.w);
    out4[2 * t]     = make_float4(pnx0, pny0, vnx0, vny0);
    out4[2 * t + 1] = make_float4(pnx1, pny1, vnx1, vny1);
}

// ---- fallback: single-pass (used only if ws_size is too small) ----
__global__ __launch_bounds__(256) void lj_onepass(const float2* __restrict__ pos,
                                                  const float2* __restrict__ vel,
                                                  const float* __restrict__ eps_p,
                                                  const float* __restrict__ sig_p,
                                                  float4* __restrict__ out) {
    __shared__ float2 sp[256];
    const int i = blockIdx.x * 256 + threadIdx.x;
    const float eps  = *eps_p, s = *sig_p;
    const float s2   = s * s, s6 = s2 * s2 * s2;
    const float ke   = 24.0f * eps;
    const float ks12 = 2.0f * ke * s6 * s6;
    const float mks6 = -ke * s6;
    const float2 pi = pos[i];
    float fx = 0.0f, fy = 0.0f;
    for (int tile = 0; tile < NAG; tile += 256) {
        __syncthreads();
        sp[threadIdx.x] = pos[tile + threadIdx.x];
        __syncthreads();
#pragma unroll 8
        for (int j = 0; j < 256; ++j) {
            const float dx = pi.x - sp[j].x, dy = pi.y - sp[j].y;
            const float r  = fmaf(dx, dx, fmaf(dy, dy, SOFT));
            const float u  = __builtin_amdgcn_rcpf(r);
            const float u2 = u * u, u3 = u2 * u, u4 = u2 * u2;
            const float c  = u4 * fmaf(ks12, u3, mks6);
            fx = fmaf(c, dx, fx); fy = fmaf(c, dy, fy);
        }
    }
    const float2 v = vel[i];
    const float vnx = fmaf(DT, fx, v.x), vny = fmaf(DT, fy, v.y);
    const float pnx = fmaf(DT, vnx, pi.x), pny = fmaf(DT, vny, pi.y);
    out[i] = make_float4(pnx, pny, vnx, vny);
}

extern "C" void kernel_launch(void* const* d_in, const int* in_sizes, int n_in,
                              void* d_out, int out_size, void* d_ws, size_t ws_size,
                              hipStream_t stream) {
    const float2* pos2  = (const float2*)d_in[0];
    const float4* pos4  = (const float4*)d_in[0];
    const float2* vel2  = (const float2*)d_in[1];
    const float4* vel4  = (const float4*)d_in[1];
    const float*  eps_p = (const float*)d_in[2];
    const float*  sig_p = (const float*)d_in[3];
    float4* out4 = (float4*)d_out;

    const size_t need = (size_t)NJC * (NAG / 2) * sizeof(float4);
    if (ws_size >= need) {
        float4* partial4 = (float4*)d_ws;
        dim3 grid1(NIB, NJC);
        lj_partial<<<grid1, BLK1, 0, stream>>>(pos4, pos2, eps_p, sig_p, partial4);
        lj_integrate<<<(NAG / 2) / BLK2, BLK2, 0, stream>>>(pos4, vel4, partial4, out4);
    } else {
        lj_onepass<<<NAG / 256, 256, 0, stream>>>(pos2, vel2, eps_p, sig_p, out4);
    }
}